// Round 4
// baseline (183.512 us; speedup 1.0000x reference)
//
#include <hip/hip_runtime.h>
#include <hip/hip_bf16.h>
#include <math.h>

typedef __bf16 bf16_t;
typedef bf16_t bf16x4 __attribute__((ext_vector_type(4)));
typedef bf16_t bf16x8 __attribute__((ext_vector_type(8)));
typedef float f32x4 __attribute__((ext_vector_type(4)));
typedef unsigned int u32;
typedef u32 u32x2 __attribute__((ext_vector_type(2)));
typedef u32 u32x4 __attribute__((ext_vector_type(4)));

#define MFMA16(a, b, c) __builtin_amdgcn_mfma_f32_16x16x32_bf16(a, b, c, 0, 0, 0)
#define NEG_BIG (-1e30f)
#define QSCALE 0.18033688f   // log2(e) / sqrt(64): folded into Q at projection

// Async global->LDS, 16B per lane. LDS dest = wave-uniform base + lane*16.
#define GLL16(gp, lp)                                                          \
    __builtin_amdgcn_global_load_lds(                                          \
        (const __attribute__((address_space(1))) unsigned int*)(gp),           \
        (__attribute__((address_space(3))) unsigned int*)(lp), 16, 0, 0)

// XOR-swizzled LDS tiles: row stride 64 elems (128B), chunk c of row r at
// slot c^(r&7). Staging lane fetches global chunk (lane&7)^(lane>>3); reads
// use slot = chunk ^ (row&7) -> 2-way max bank aliasing (free, m136).

// ---------------------------------------------------------------------------
// Fused prep: z=4 -> cast x to bf16 (4 passes: 1024 blocks cover 4M elems);
// z=0..3 -> transpose+cast Wq/Wk/Wv/Wo. Grid (32,32,5), block (32,8).
// ---------------------------------------------------------------------------
__global__ __launch_bounds__(256) void prep(const float* __restrict__ x,
                                            const float* __restrict__ Wq,
                                            const float* __restrict__ Wk,
                                            const float* __restrict__ Wv,
                                            const float* __restrict__ Wo,
                                            bf16_t* __restrict__ Xb,
                                            bf16_t* __restrict__ WTqkv,
                                            bf16_t* __restrict__ WoT) {
    __shared__ float tile[32][33];
    const int z = blockIdx.z;
    const int tx = threadIdx.x, ty = threadIdx.y;
    if (z == 4) {
        int i0 = (((blockIdx.y * 32 + blockIdx.x) * 256) + ty * 32 + tx) * 4;
        for (int j = 0; j < 4; j++) {
            int i = i0 + j * 1048576;
            float4 v = *(const float4*)(x + i);
            Xb[i + 0] = (bf16_t)v.x;
            Xb[i + 1] = (bf16_t)v.y;
            Xb[i + 2] = (bf16_t)v.z;
            Xb[i + 3] = (bf16_t)v.w;
        }
    } else {
        const float* W = (z == 0) ? Wq : (z == 1) ? Wk : (z == 2) ? Wv : Wo;
        bf16_t* WT = (z < 3) ? (WTqkv + (size_t)z * 1048576) : WoT;
        int bx = blockIdx.x * 32, by = blockIdx.y * 32;
        for (int i = 0; i < 32; i += 8)
            tile[ty + i][tx] = W[(size_t)(by + ty + i) * 1024 + bx + tx];
        __syncthreads();
        for (int i = 0; i < 32; i += 8)
            WT[(size_t)(bx + ty + i) * 1024 + by + tx] = (bf16_t)tile[tx][ty + i];
    }
}

// ---------------------------------------------------------------------------
// QKV projection GEMM, 2-phase double-buffered global_load_lds pipeline.
// 128x128 tile, 4 waves 2x2, BK=64, LDS 64 KiB (2 blocks/CU), XCD swizzle.
// (Kept from round 3 — improved 51.4 -> <43.6 us.)
// ---------------------------------------------------------------------------
__global__ __launch_bounds__(256) void gemm_qkv(const bf16_t* __restrict__ X,
                                                const bf16_t* __restrict__ WT,
                                                bf16_t* __restrict__ Qd,
                                                bf16_t* __restrict__ Kd,
                                                bf16_t* __restrict__ Vd) {
    __shared__ bf16_t AsmF[2][128 * 64];
    __shared__ bf16_t BsmF[2][128 * 64];
    const int bid = blockIdx.x;                     // 768 blocks
    const int logical = (bid & 7) * 96 + (bid >> 3); // XCD-contiguous
    const int which = logical >> 8;                  // 0..2
    const int rem = logical & 255;
    const bf16_t* Wt = WT + (size_t)which * 1024 * 1024;
    const int bm = (rem >> 3) * 128;
    const int bn = (rem & 7) * 128;
    const int tid = threadIdx.x;
    const int wave = tid >> 6, lane = tid & 63;
    const int wm = (wave >> 1) * 64, wn = (wave & 1) * 64;
    const int col = lane & 15, quad = lane >> 4;
    const int cswz = col & 7;
    const int lr8 = lane >> 3;
    const int jg = (lane & 7) ^ lr8;

    const int srow = wave * 32 + lr8;
    const bf16_t* gA = X  + (size_t)(bm + srow) * 1024 + jg * 8;
    const bf16_t* gB = Wt + (size_t)(bn + srow) * 1024 + jg * 8;

    auto stage = [&](int k0, int bsel) {
        bf16_t* lA = AsmF[bsel] + wave * 2048;
        bf16_t* lB = BsmF[bsel] + wave * 2048;
        for (int j = 0; j < 4; j++) {
            GLL16(gA + (size_t)j * 8192 + k0, lA + j * 512);
            GLL16(gB + (size_t)j * 8192 + k0, lB + j * 512);
        }
    };

    stage(0, 0);  // prologue

    f32x4 acc[4][4] = {};

    for (int t = 0; t < 16; t++) {
        __syncthreads();   // drains stage(t) (vmcnt 0) + all waves done reading buf^1
        if (t + 1 < 16) stage((t + 1) * 64, (t + 1) & 1);
        const bf16_t* Ab = AsmF[t & 1];
        const bf16_t* Bb = BsmF[t & 1];
        for (int ks = 0; ks < 2; ks++) {
            bf16x8 af[4], bfr[4];
            for (int mi = 0; mi < 4; mi++)
                af[mi] = *(const bf16x8*)&Ab[(wm + mi * 16 + col) * 64 +
                                             (((ks << 2) + quad) ^ cswz) * 8];
            for (int ni = 0; ni < 4; ni++)
                bfr[ni] = *(const bf16x8*)&Bb[(wn + ni * 16 + col) * 64 +
                                              (((ks << 2) + quad) ^ cswz) * 8];
            if (which != 2) {
                for (int mi = 0; mi < 4; mi++)
                    for (int ni = 0; ni < 4; ni++)
                        acc[mi][ni] = MFMA16(af[mi], bfr[ni], acc[mi][ni]);
            } else {
                for (int mi = 0; mi < 4; mi++)
                    for (int ni = 0; ni < 4; ni++)
                        acc[mi][ni] = MFMA16(bfr[ni], af[mi], acc[mi][ni]);
            }
        }
    }

    if (which != 2) {
        const float sc = (which == 0) ? QSCALE : 1.0f;
        for (int mi = 0; mi < 4; mi++) {
            for (int ni = 0; ni < 4; ni++) {
                int mbase = bm + wm + mi * 16 + quad * 4;
                int n = bn + wn + ni * 16 + col;
                int h = n >> 6, dh = n & 63;
                for (int r = 0; r < 4; r++) {
                    int m = mbase + r;
                    int b = m >> 11, s = m & 2047;
                    size_t bh = (size_t)b * 16 + h;
                    bf16_t val = (bf16_t)(acc[mi][ni][r] * sc);
                    if (which == 0) Qd[(bh * 2048 + s) * 64 + dh] = val;
                    else            Kd[(bh * 2048 + s) * 64 + dh] = val;
                }
            }
        }
    } else {
        for (int mi = 0; mi < 4; mi++) {
            for (int ni = 0; ni < 4; ni++) {
                int nbase = bn + wn + ni * 16 + quad * 4;
                int m = bm + wm + mi * 16 + col;
                int b = m >> 11, s = m & 2047;
                for (int r = 0; r < 4; r++) {
                    int n = nbase + r;
                    int h = n >> 6, dh = n & 63;
                    size_t bh = (size_t)b * 16 + h;
                    Vd[(bh * 64 + dh) * 2048 + s] = (bf16_t)acc[mi][ni][r];
                }
            }
        }
    }
}

// ---------------------------------------------------------------------------
// Flash attention (causal): ONE 64-q tile per block, grid 1024, block = 128
// threads (2 waves). Each wave computes TWO 16-row q-groups (32 q-rows) per
// K/V tile read -> LDS ds_read amplification halved vs 4x16 (the measured
// LDS-pipe wall, ~72% occupied). LDS 32 KiB -> 5 blocks/CU (10 waves).
// P transpose: dual ds_bpermute + dest-side select (quad>>1), per group.
// ---------------------------------------------------------------------------
__global__ __launch_bounds__(128) void attn(const bf16_t* __restrict__ Q,
                                            const bf16_t* __restrict__ K,
                                            const bf16_t* __restrict__ VT,
                                            bf16_t* __restrict__ CTX) {
    __shared__ bf16_t KsF[2 * 64 * 64];
    __shared__ bf16_t VsF[2 * 64 * 64];

    const int bidx = blockIdx.x;
    const int bh = bidx & 31;        // XCD-local: bidx%8 == bh%8
    const int qt = 31 - (bidx >> 5); // longest-first dispatch order
    const int tid = threadIdx.x;
    const int wave = tid >> 6, lane = tid & 63;   // wave in {0,1}
    const int col = lane & 15, quad = lane >> 4;
    const int cswz = col & 7;
    const int lr8 = lane >> 3;
    const int jg = (lane & 7) ^ lr8;

    const bf16_t* Qb = Q + (size_t)bh * 2048 * 64;
    const bf16_t* Kb = K + (size_t)bh * 2048 * 64;
    const bf16_t* Vb = VT + (size_t)bh * 64 * 2048;

    const int strow = wave * 32 + lr8;
    const bf16_t* gK = Kb + (size_t)strow * 64 + jg * 8;
    const bf16_t* gV = Vb + (size_t)strow * 2048 + jg * 8;

    const int b_ = bh >> 4, h_ = bh & 15;

    bf16x8 ones;
    for (int i = 0; i < 8; i++) ones[i] = (bf16_t)1.0f;

    auto stage = [&](int k0, int bsel) {
        bf16_t* lK = KsF + bsel * 4096 + wave * 2048;
        bf16_t* lV = VsF + bsel * 4096 + wave * 2048;
        for (int j = 0; j < 4; j++) {
            GLL16(gK + (size_t)(k0 + j * 8) * 64, lK + j * 512);
            GLL16(gV + (size_t)(k0 + j * 8 * 2048), lV + j * 512);
        }
    };

    stage(0, 0);  // prologue

    const int q0 = qt * 64;
    // group G (0,1): q-rows q0 + wave*32 + G*16 + col
    const int qrA = q0 + wave * 32 + col;
    const bf16x8 qfA0 = *(const bf16x8*)&Qb[(size_t)qrA * 64 + quad * 8];
    const bf16x8 qfA1 = *(const bf16x8*)&Qb[(size_t)qrA * 64 + 32 + quad * 8];
    const bf16x8 qfB0 = *(const bf16x8*)&Qb[(size_t)(qrA + 16) * 64 + quad * 8];
    const bf16x8 qfB1 = *(const bf16x8*)&Qb[(size_t)(qrA + 16) * 64 + 32 + quad * 8];

    f32x4 o[2][4] = {};
    f32x4 accl[2] = {};  // per group: reg r holds l[quad*4+r]

    // bpermute source lane (byte addr) and dest-side ksub selector
    const int iA = (col | ((quad & 1) << 5)) << 2;
    const bool hi = (quad & 2) != 0;   // dest needs ksub = 2*ck + (quad>>1)

    const int nt = qt + 1;
    for (int g = 0; g < nt; g++) {
        __syncthreads();   // buf[g&1] ready; compute(g-1) done -> buf[(g+1)&1] free
        if (g + 1 < nt) stage((g + 1) * 64, (g + 1) & 1);

        const int bsel = g & 1;
        const bf16_t* Kbuf = KsF + bsel * 4096;
        const bf16_t* Vbuf = VsF + bsel * 4096;
        const bool diag = (g == qt);

        u32x2 pwd[2][4];
#pragma unroll
        for (int ksub = 0; ksub < 4; ksub++) {
            bf16x8 a0 = *(const bf16x8*)&Kbuf[(ksub * 16 + col) * 64 +
                                              (quad ^ cswz) * 8];
            bf16x8 a1 = *(const bf16x8*)&Kbuf[(ksub * 16 + col) * 64 +
                                              ((4 + quad) ^ cswz) * 8];
#pragma unroll
            for (int G = 0; G < 2; G++) {
                f32x4 z = {};
                z = MFMA16(a0, G ? qfB0 : qfA0, z);  // S^T rows=key cols=q
                z = MFMA16(a1, G ? qfB1 : qfA1, z);
                if (diag) {
                    int qloc = wave * 32 + G * 16 + col;
                    for (int r = 0; r < 4; r++) {
                        int lk = ksub * 16 + quad * 4 + r;
                        if (lk > qloc) z[r] = NEG_BIG;
                    }
                }
                bf16x4 pw;
#pragma unroll
                for (int r = 0; r < 4; r++)
                    pw[r] = (bf16_t)__builtin_amdgcn_exp2f(z[r]);
                pwd[G][ksub] = __builtin_bit_cast(u32x2, pw);
            }
        }

#pragma unroll
        for (int ck = 0; ck < 2; ck++) {
            bf16x8 vf[4];
#pragma unroll
            for (int d = 0; d < 4; d++)
                vf[d] = *(const bf16x8*)&Vbuf[(d * 16 + col) * 64 +
                                              (((ck << 2) + quad) ^ cswz) * 8];
#pragma unroll
            for (int G = 0; G < 2; G++) {
                u32x2 sA = pwd[G][2 * ck], sB = pwd[G][2 * ck + 1];
                int w0a = __builtin_amdgcn_ds_bpermute(iA,      (int)sA.x);
                int w0b = __builtin_amdgcn_ds_bpermute(iA,      (int)sB.x);
                int w1a = __builtin_amdgcn_ds_bpermute(iA,      (int)sA.y);
                int w1b = __builtin_amdgcn_ds_bpermute(iA,      (int)sB.y);
                int w2a = __builtin_amdgcn_ds_bpermute(iA + 64, (int)sA.x);
                int w2b = __builtin_amdgcn_ds_bpermute(iA + 64, (int)sB.x);
                int w3a = __builtin_amdgcn_ds_bpermute(iA + 64, (int)sA.y);
                int w3b = __builtin_amdgcn_ds_bpermute(iA + 64, (int)sB.y);
                u32x4 pu = {(u32)(hi ? w0b : w0a), (u32)(hi ? w1b : w1a),
                            (u32)(hi ? w2b : w2a), (u32)(hi ? w3b : w3a)};
                bf16x8 pf = __builtin_bit_cast(bf16x8, pu);

                accl[G] = MFMA16(pf, ones, accl[G]);  // l[q] += sum_k P[q][k]
                for (int d = 0; d < 4; d++)
                    o[G][d] = MFMA16(pf, vf[d], o[G][d]);
            }
        }
    }

#pragma unroll
    for (int G = 0; G < 2; G++) {
        for (int r = 0; r < 4; r++) {
            float rl = __builtin_amdgcn_rcpf(fmaxf(accl[G][r], 1e-20f));
            int s = q0 + wave * 32 + G * 16 + quad * 4 + r;
            for (int d = 0; d < 4; d++) {
                CTX[((size_t)(b_ * 2048 + s)) * 1024 + h_ * 64 + d * 16 + col] =
                    (bf16_t)(o[G][d][r] * rl);
            }
        }
    }
}

// ---------------------------------------------------------------------------
// Output GEMM: OUT = CTX @ Wo + bo. 64x128 tile, BK=64, SINGLE-buffered
// m97-style (24 KiB LDS -> 6 blocks/CU; dbuf regressed this kernel by
// halving occupancy). XCD-swizzled 1-D grid (64 tiles/XCD).
// ---------------------------------------------------------------------------
__global__ __launch_bounds__(256) void gemm_out(const bf16_t* __restrict__ X,
                                                const bf16_t* __restrict__ WT,
                                                const float* __restrict__ BO,
                                                float* __restrict__ OUT) {
    __shared__ bf16_t AsmF[64 * 64];
    __shared__ bf16_t BsmF[128 * 64];
    const int bid = blockIdx.x;                     // 512 blocks
    const int logical = (bid & 7) * 64 + (bid >> 3); // XCD-contiguous
    const int bm = (logical >> 3) * 64;
    const int bn = (logical & 7) * 128;
    const int tid = threadIdx.x;
    const int wave = tid >> 6, lane = tid & 63;
    const int wm = (wave >> 1) * 32, wn = (wave & 1) * 64;
    const int col = lane & 15, quad = lane >> 4;
    const int cswz = col & 7;
    const int lr8 = lane >> 3;
    const int jg = (lane & 7) ^ lr8;

    const int arow = wave * 16 + lr8;
    const int brow = wave * 32 + lr8;
    const bf16_t* gA = X  + (size_t)(bm + arow) * 1024 + jg * 8;
    const bf16_t* gB = WT + (size_t)(bn + brow) * 1024 + jg * 8;
    bf16_t* lA = AsmF + wave * 1024;
    bf16_t* lB = BsmF + wave * 2048;

    f32x4 acc[2][4] = {};

    for (int k0 = 0; k0 < 1024; k0 += 64) {
        for (int j = 0; j < 2; j++)
            GLL16(gA + (size_t)j * 8192 + k0, lA + j * 512);
        for (int j = 0; j < 4; j++)
            GLL16(gB + (size_t)j * 8192 + k0, lB + j * 512);
        __syncthreads();
        for (int ks = 0; ks < 2; ks++) {
            bf16x8 af[2], bfr[4];
            for (int mi = 0; mi < 2; mi++)
                af[mi] = *(const bf16x8*)&AsmF[(wm + mi * 16 + col) * 64 +
                                               (((ks << 2) + quad) ^ cswz) * 8];
            for (int ni = 0; ni < 4; ni++)
                bfr[ni] = *(const bf16x8*)&BsmF[(wn + ni * 16 + col) * 64 +
                                                (((ks << 2) + quad) ^ cswz) * 8];
            for (int mi = 0; mi < 2; mi++)
                for (int ni = 0; ni < 4; ni++)
                    acc[mi][ni] = MFMA16(af[mi], bfr[ni], acc[mi][ni]);
        }
        __syncthreads();
    }

    for (int mi = 0; mi < 2; mi++) {
        for (int ni = 0; ni < 4; ni++) {
            int mbase = bm + wm + mi * 16 + quad * 4;
            int n = bn + wn + ni * 16 + col;
            float bov = BO[n];
            for (int r = 0; r < 4; r++) {
                int m = mbase + r;
                OUT[(size_t)m * 1024 + n] = acc[mi][ni][r] + bov;
            }
        }
    }
}

// ---------------------------------------------------------------------------
extern "C" void kernel_launch(void* const* d_in, const int* in_sizes, int n_in,
                              void* d_out, int out_size, void* d_ws, size_t ws_size,
                              hipStream_t stream) {
    const float* x  = (const float*)d_in[0];
    const float* Wq = (const float*)d_in[1];
    const float* Wk = (const float*)d_in[2];
    const float* Wv = (const float*)d_in[3];
    const float* Wo = (const float*)d_in[4];
    const float* bo = (const float*)d_in[5];
    float* out = (float*)d_out;

    const size_t MEG = 1048576;
    bf16_t* base  = (bf16_t*)d_ws;
    bf16_t* Xb    = base;                 // 4M elems  [4096][1024]
    bf16_t* WTqkv = base + 4 * MEG;       // 3M (WqT, WkT, WvT)
    bf16_t* WoT   = base + 7 * MEG;       // 1M
    bf16_t* Qb    = base + 8 * MEG;       // 4M  [32][2048][64]
    bf16_t* Kb    = base + 12 * MEG;      // 4M
    bf16_t* Vb    = base + 16 * MEG;      // 4M  [32][64][2048]
    bf16_t* Cb    = base + 20 * MEG;      // 4M  [4096][1024]

    prep<<<dim3(32, 32, 5), dim3(32, 8), 0, stream>>>(x, Wq, Wk, Wv, Wo,
                                                      Xb, WTqkv, WoT);
    gemm_qkv<<<768, 256, 0, stream>>>(Xb, WTqkv, Qb, Kb, Vb);
    attn<<<1024, 128, 0, stream>>>(Qb, Kb, Vb, Cb);
    gemm_out<<<512, 256, 0, stream>>>(Cb, WoT, bo, out);
}

// Round 5
// 172.752 us; speedup vs baseline: 1.0623x; 1.0623x over previous
//
#include <hip/hip_runtime.h>
#include <hip/hip_bf16.h>
#include <math.h>

typedef __bf16 bf16_t;
typedef bf16_t bf16x4 __attribute__((ext_vector_type(4)));
typedef bf16_t bf16x8 __attribute__((ext_vector_type(8)));
typedef float f32x4 __attribute__((ext_vector_type(4)));
typedef unsigned int u32;
typedef u32 u32x2 __attribute__((ext_vector_type(2)));
typedef u32 u32x4 __attribute__((ext_vector_type(4)));

#define MFMA16(a, b, c) __builtin_amdgcn_mfma_f32_16x16x32_bf16(a, b, c, 0, 0, 0)
#define NEG_BIG (-1e30f)
#define QSCALE 0.18033688f   // log2(e) / sqrt(64): folded into Q at projection

// Async global->LDS, 16B per lane. LDS dest = wave-uniform base + lane*16.
#define GLL16(gp, lp)                                                          \
    __builtin_amdgcn_global_load_lds(                                          \
        (const __attribute__((address_space(1))) unsigned int*)(gp),           \
        (__attribute__((address_space(3))) unsigned int*)(lp), 16, 0, 0)

// XOR-swizzled LDS tiles: row stride 64 elems (128B), chunk c of row r at
// slot c^(r&7). Staging lane fetches global chunk (lane&7)^(lane>>3); reads
// use slot = chunk ^ (row&7) -> 2-way max bank aliasing (free, m136).

// ---------------------------------------------------------------------------
// Fused prep: z=4 -> cast x to bf16 (4 passes: 1024 blocks cover 4M elems);
// z=0..3 -> transpose+cast Wq/Wk/Wv/Wo. Grid (32,32,5), block (32,8).
// ---------------------------------------------------------------------------
__global__ __launch_bounds__(256) void prep(const float* __restrict__ x,
                                            const float* __restrict__ Wq,
                                            const float* __restrict__ Wk,
                                            const float* __restrict__ Wv,
                                            const float* __restrict__ Wo,
                                            bf16_t* __restrict__ Xb,
                                            bf16_t* __restrict__ WTqkv,
                                            bf16_t* __restrict__ WoT) {
    __shared__ float tile[32][33];
    const int z = blockIdx.z;
    const int tx = threadIdx.x, ty = threadIdx.y;
    if (z == 4) {
        int i0 = (((blockIdx.y * 32 + blockIdx.x) * 256) + ty * 32 + tx) * 4;
        for (int j = 0; j < 4; j++) {
            int i = i0 + j * 1048576;
            float4 v = *(const float4*)(x + i);
            Xb[i + 0] = (bf16_t)v.x;
            Xb[i + 1] = (bf16_t)v.y;
            Xb[i + 2] = (bf16_t)v.z;
            Xb[i + 3] = (bf16_t)v.w;
        }
    } else {
        const float* W = (z == 0) ? Wq : (z == 1) ? Wk : (z == 2) ? Wv : Wo;
        bf16_t* WT = (z < 3) ? (WTqkv + (size_t)z * 1048576) : WoT;
        int bx = blockIdx.x * 32, by = blockIdx.y * 32;
        for (int i = 0; i < 32; i += 8)
            tile[ty + i][tx] = W[(size_t)(by + ty + i) * 1024 + bx + tx];
        __syncthreads();
        for (int i = 0; i < 32; i += 8)
            WT[(size_t)(bx + ty + i) * 1024 + by + tx] = (bf16_t)tile[tx][ty + i];
    }
}

// ---------------------------------------------------------------------------
// QKV projection GEMM, 2-phase double-buffered global_load_lds pipeline.
// 128x128 tile, 4 waves 2x2, BK=64, LDS 64 KiB (2 blocks/CU), XCD swizzle.
// ---------------------------------------------------------------------------
__global__ __launch_bounds__(256) void gemm_qkv(const bf16_t* __restrict__ X,
                                                const bf16_t* __restrict__ WT,
                                                bf16_t* __restrict__ Qd,
                                                bf16_t* __restrict__ Kd,
                                                bf16_t* __restrict__ Vd) {
    __shared__ bf16_t AsmF[2][128 * 64];
    __shared__ bf16_t BsmF[2][128 * 64];
    const int bid = blockIdx.x;                     // 768 blocks
    const int logical = (bid & 7) * 96 + (bid >> 3); // XCD-contiguous
    const int which = logical >> 8;                  // 0..2
    const int rem = logical & 255;
    const bf16_t* Wt = WT + (size_t)which * 1024 * 1024;
    const int bm = (rem >> 3) * 128;
    const int bn = (rem & 7) * 128;
    const int tid = threadIdx.x;
    const int wave = tid >> 6, lane = tid & 63;
    const int wm = (wave >> 1) * 64, wn = (wave & 1) * 64;
    const int col = lane & 15, quad = lane >> 4;
    const int cswz = col & 7;
    const int lr8 = lane >> 3;
    const int jg = (lane & 7) ^ lr8;

    const int srow = wave * 32 + lr8;
    const bf16_t* gA = X  + (size_t)(bm + srow) * 1024 + jg * 8;
    const bf16_t* gB = Wt + (size_t)(bn + srow) * 1024 + jg * 8;

    auto stage = [&](int k0, int bsel) {
        bf16_t* lA = AsmF[bsel] + wave * 2048;
        bf16_t* lB = BsmF[bsel] + wave * 2048;
        for (int j = 0; j < 4; j++) {
            GLL16(gA + (size_t)j * 8192 + k0, lA + j * 512);
            GLL16(gB + (size_t)j * 8192 + k0, lB + j * 512);
        }
    };

    stage(0, 0);  // prologue

    f32x4 acc[4][4] = {};

    for (int t = 0; t < 16; t++) {
        __syncthreads();   // drains stage(t) (vmcnt 0) + all waves done reading buf^1
        if (t + 1 < 16) stage((t + 1) * 64, (t + 1) & 1);
        const bf16_t* Ab = AsmF[t & 1];
        const bf16_t* Bb = BsmF[t & 1];
        for (int ks = 0; ks < 2; ks++) {
            bf16x8 af[4], bfr[4];
            for (int mi = 0; mi < 4; mi++)
                af[mi] = *(const bf16x8*)&Ab[(wm + mi * 16 + col) * 64 +
                                             (((ks << 2) + quad) ^ cswz) * 8];
            for (int ni = 0; ni < 4; ni++)
                bfr[ni] = *(const bf16x8*)&Bb[(wn + ni * 16 + col) * 64 +
                                              (((ks << 2) + quad) ^ cswz) * 8];
            if (which != 2) {
                for (int mi = 0; mi < 4; mi++)
                    for (int ni = 0; ni < 4; ni++)
                        acc[mi][ni] = MFMA16(af[mi], bfr[ni], acc[mi][ni]);
            } else {
                for (int mi = 0; mi < 4; mi++)
                    for (int ni = 0; ni < 4; ni++)
                        acc[mi][ni] = MFMA16(bfr[ni], af[mi], acc[mi][ni]);
            }
        }
    }

    if (which != 2) {
        const float sc = (which == 0) ? QSCALE : 1.0f;
        for (int mi = 0; mi < 4; mi++) {
            for (int ni = 0; ni < 4; ni++) {
                int mbase = bm + wm + mi * 16 + quad * 4;
                int n = bn + wn + ni * 16 + col;
                int h = n >> 6, dh = n & 63;
                for (int r = 0; r < 4; r++) {
                    int m = mbase + r;
                    int b = m >> 11, s = m & 2047;
                    size_t bh = (size_t)b * 16 + h;
                    bf16_t val = (bf16_t)(acc[mi][ni][r] * sc);
                    if (which == 0) Qd[(bh * 2048 + s) * 64 + dh] = val;
                    else            Kd[(bh * 2048 + s) * 64 + dh] = val;
                }
            }
        }
    } else {
        for (int mi = 0; mi < 4; mi++) {
            for (int ni = 0; ni < 4; ni++) {
                int nbase = bn + wn + ni * 16 + quad * 4;
                int m = bm + wm + mi * 16 + col;
                int b = m >> 11, s = m & 2047;
                for (int r = 0; r < 4; r++) {
                    int n = nbase + r;
                    int h = n >> 6, dh = n & 63;
                    size_t bh = (size_t)b * 16 + h;
                    Vd[(bh * 64 + dh) * 2048 + s] = (bf16_t)acc[mi][ni][r];
                }
            }
        }
    }
}

// ---------------------------------------------------------------------------
// Flash attention (causal): 64-q tile per block, grid 1024, 4 waves = 2x2
// (qhalf x khalf). Each wave: 32 q-rows x 32 keys -> K/V ds_reads per tile
// halved vs r3 (8 b128 instead of 16) while KEEPING 20 waves/CU (r4's
// regression was the wave-count cut, not the amortization).
// No running max needed (pure sums): khalf partials of o/l are reduced once
// at the end through LDS. P transpose: dual ds_bpermute + dest-side select
// (identical lane math to r3: sources col|((quad&1)<<5), +16; sel quad>>1).
// ---------------------------------------------------------------------------
__global__ __launch_bounds__(256) void attn(const bf16_t* __restrict__ Q,
                                            const bf16_t* __restrict__ K,
                                            const bf16_t* __restrict__ VT,
                                            bf16_t* __restrict__ CTX) {
    __shared__ __align__(16) bf16_t SMEM[16384];   // 32 KiB: K(2x4096) V(2x4096)
    bf16_t* KsF = SMEM;
    bf16_t* VsF = SMEM + 8192;

    const int bidx = blockIdx.x;
    const int bh = bidx & 31;        // XCD-local: bidx%8 == bh%8
    const int qt = 31 - (bidx >> 5); // longest-first dispatch order
    const int tid = threadIdx.x;
    const int wave = tid >> 6, lane = tid & 63;
    const int qhalf = wave & 1, khalf = wave >> 1;
    const int col = lane & 15, quad = lane >> 4;
    const int cswz = col & 7;
    const int lr8 = lane >> 3;
    const int jg = (lane & 7) ^ lr8;

    const bf16_t* Qb = Q + (size_t)bh * 2048 * 64;
    const bf16_t* Kb = K + (size_t)bh * 2048 * 64;
    const bf16_t* Vb = VT + (size_t)bh * 64 * 2048;

    const int strow = wave * 16 + lr8;
    const bf16_t* gK = Kb + (size_t)strow * 64 + jg * 8;
    const bf16_t* gV = Vb + (size_t)strow * 2048 + jg * 8;

    const int b_ = bh >> 4, h_ = bh & 15;

    bf16x8 ones;
    for (int i = 0; i < 8; i++) ones[i] = (bf16_t)1.0f;

    auto stage = [&](int k0, int bsel) {
        bf16_t* lK = KsF + bsel * 4096 + wave * 1024;
        bf16_t* lV = VsF + bsel * 4096 + wave * 1024;
        for (int j = 0; j < 2; j++) {
            GLL16(gK + (size_t)(k0 + j * 8) * 64, lK + j * 512);
            GLL16(gV + (size_t)(k0 + j * 8 * 2048), lV + j * 512);
        }
    };

    stage(0, 0);  // prologue

    const int q0 = qt * 64;
    // group G (0,1): q-rows q0 + qhalf*32 + G*16 + col
    const int qrA = q0 + qhalf * 32 + col;
    const bf16x8 qfA0 = *(const bf16x8*)&Qb[(size_t)qrA * 64 + quad * 8];
    const bf16x8 qfA1 = *(const bf16x8*)&Qb[(size_t)qrA * 64 + 32 + quad * 8];
    const bf16x8 qfB0 = *(const bf16x8*)&Qb[(size_t)(qrA + 16) * 64 + quad * 8];
    const bf16x8 qfB1 = *(const bf16x8*)&Qb[(size_t)(qrA + 16) * 64 + 32 + quad * 8];

    f32x4 o[2][4] = {};
    f32x4 accl[2] = {};  // per group: reg r holds l[quad*4+r] (partial: khalf)

    // bpermute source lane (byte addr) and dest-side ksub selector
    const int iA = (col | ((quad & 1) << 5)) << 2;
    const bool hi = (quad & 2) != 0;   // dest needs local ksub = quad>>1

    const int nt = qt + 1;
    for (int g = 0; g < nt; g++) {
        __syncthreads();   // buf[g&1] ready; compute(g-1) done -> buf[(g+1)&1] free
        if (g + 1 < nt) stage((g + 1) * 64, (g + 1) & 1);

        const int bsel = g & 1;
        const bf16_t* Kbuf = KsF + bsel * 4096;
        const bf16_t* Vbuf = VsF + bsel * 4096;
        const bool diag = (g == qt);

        u32x2 pwd[2][2];   // [G][local ksub]
#pragma unroll
        for (int ksl = 0; ksl < 2; ksl++) {
            const int ksub = khalf * 2 + ksl;      // global 16-key group in tile
            bf16x8 a0 = *(const bf16x8*)&Kbuf[(ksub * 16 + col) * 64 +
                                              (quad ^ cswz) * 8];
            bf16x8 a1 = *(const bf16x8*)&Kbuf[(ksub * 16 + col) * 64 +
                                              ((4 + quad) ^ cswz) * 8];
#pragma unroll
            for (int G = 0; G < 2; G++) {
                f32x4 z = {};
                z = MFMA16(a0, G ? qfB0 : qfA0, z);  // S^T rows=key cols=q
                z = MFMA16(a1, G ? qfB1 : qfA1, z);
                if (diag) {
                    int qloc = qhalf * 32 + G * 16 + col;
                    for (int r = 0; r < 4; r++) {
                        int lk = ksub * 16 + quad * 4 + r;
                        if (lk > qloc) z[r] = NEG_BIG;
                    }
                }
                bf16x4 pw;
#pragma unroll
                for (int r = 0; r < 4; r++)
                    pw[r] = (bf16_t)__builtin_amdgcn_exp2f(z[r]);
                pwd[G][ksl] = __builtin_bit_cast(u32x2, pw);
            }
        }

        // PV over this wave's 32 keys (khalf selects V chunk range)
        bf16x8 vf[4];
#pragma unroll
        for (int d = 0; d < 4; d++)
            vf[d] = *(const bf16x8*)&Vbuf[(d * 16 + col) * 64 +
                                          (((khalf << 2) + quad) ^ cswz) * 8];
#pragma unroll
        for (int G = 0; G < 2; G++) {
            u32x2 sA = pwd[G][0], sB = pwd[G][1];
            int w0a = __builtin_amdgcn_ds_bpermute(iA,      (int)sA.x);
            int w0b = __builtin_amdgcn_ds_bpermute(iA,      (int)sB.x);
            int w1a = __builtin_amdgcn_ds_bpermute(iA,      (int)sA.y);
            int w1b = __builtin_amdgcn_ds_bpermute(iA,      (int)sB.y);
            int w2a = __builtin_amdgcn_ds_bpermute(iA + 64, (int)sA.x);
            int w2b = __builtin_amdgcn_ds_bpermute(iA + 64, (int)sB.x);
            int w3a = __builtin_amdgcn_ds_bpermute(iA + 64, (int)sA.y);
            int w3b = __builtin_amdgcn_ds_bpermute(iA + 64, (int)sB.y);
            u32x4 pu = {(u32)(hi ? w0b : w0a), (u32)(hi ? w1b : w1a),
                        (u32)(hi ? w2b : w2a), (u32)(hi ? w3b : w3a)};
            bf16x8 pf = __builtin_bit_cast(bf16x8, pu);

            accl[G] = MFMA16(pf, ones, accl[G]);  // partial l over 32 keys
            for (int d = 0; d < 4; d++)
                o[G][d] = MFMA16(pf, vf[d], o[G][d]);
        }
    }

    // ----- cross-wave (khalf) reduction of o/accl through LDS, then store.
    __syncthreads();                       // everyone done reading K/V LDS
    float* ex = (float*)SMEM;              // 2 waves x 64 lanes x 48 f32 = 24KB
    if (khalf == 1) {
        float* p = ex + qhalf * 3072 + lane * 48;
#pragma unroll
        for (int G = 0; G < 2; G++)
            for (int d = 0; d < 4; d++)
                *(f32x4*)(p + (G * 4 + d) * 4) = o[G][d];
        *(f32x4*)(p + 32) = accl[0];
        *(f32x4*)(p + 36) = accl[1];
    }
    __syncthreads();
    if (khalf == 0) {
        float* p = ex + qhalf * 3072 + lane * 48;
#pragma unroll
        for (int G = 0; G < 2; G++)
            for (int d = 0; d < 4; d++)
                o[G][d] += *(const f32x4*)(p + (G * 4 + d) * 4);
        accl[0] += *(const f32x4*)(p + 32);
        accl[1] += *(const f32x4*)(p + 36);

#pragma unroll
        for (int G = 0; G < 2; G++) {
            for (int r = 0; r < 4; r++) {
                float rl = __builtin_amdgcn_rcpf(fmaxf(accl[G][r], 1e-20f));
                int s = q0 + qhalf * 32 + G * 16 + quad * 4 + r;
                for (int d = 0; d < 4; d++) {
                    CTX[((size_t)(b_ * 2048 + s)) * 1024 + h_ * 64 + d * 16 + col] =
                        (bf16_t)(o[G][d][r] * rl);
                }
            }
        }
    }
}

// ---------------------------------------------------------------------------
// Output GEMM: OUT = CTX @ Wo + bo. 64x128 tile, BK=64, SINGLE-buffered
// m97-style (24 KiB LDS -> 6 blocks/CU; dbuf regressed this kernel by
// halving occupancy). XCD-swizzled 1-D grid (64 tiles/XCD).
// ---------------------------------------------------------------------------
__global__ __launch_bounds__(256) void gemm_out(const bf16_t* __restrict__ X,
                                                const bf16_t* __restrict__ WT,
                                                const float* __restrict__ BO,
                                                float* __restrict__ OUT) {
    __shared__ bf16_t AsmF[64 * 64];
    __shared__ bf16_t BsmF[128 * 64];
    const int bid = blockIdx.x;                     // 512 blocks
    const int logical = (bid & 7) * 64 + (bid >> 3); // XCD-contiguous
    const int bm = (logical >> 3) * 64;
    const int bn = (logical & 7) * 128;
    const int tid = threadIdx.x;
    const int wave = tid >> 6, lane = tid & 63;
    const int wm = (wave >> 1) * 32, wn = (wave & 1) * 64;
    const int col = lane & 15, quad = lane >> 4;
    const int cswz = col & 7;
    const int lr8 = lane >> 3;
    const int jg = (lane & 7) ^ lr8;

    const int arow = wave * 16 + lr8;
    const int brow = wave * 32 + lr8;
    const bf16_t* gA = X  + (size_t)(bm + arow) * 1024 + jg * 8;
    const bf16_t* gB = WT + (size_t)(bn + brow) * 1024 + jg * 8;
    bf16_t* lA = AsmF + wave * 1024;
    bf16_t* lB = BsmF + wave * 2048;

    f32x4 acc[2][4] = {};

    for (int k0 = 0; k0 < 1024; k0 += 64) {
        for (int j = 0; j < 2; j++)
            GLL16(gA + (size_t)j * 8192 + k0, lA + j * 512);
        for (int j = 0; j < 4; j++)
            GLL16(gB + (size_t)j * 8192 + k0, lB + j * 512);
        __syncthreads();
        for (int ks = 0; ks < 2; ks++) {
            bf16x8 af[2], bfr[4];
            for (int mi = 0; mi < 2; mi++)
                af[mi] = *(const bf16x8*)&AsmF[(wm + mi * 16 + col) * 64 +
                                               (((ks << 2) + quad) ^ cswz) * 8];
            for (int ni = 0; ni < 4; ni++)
                bfr[ni] = *(const bf16x8*)&BsmF[(wn + ni * 16 + col) * 64 +
                                                (((ks << 2) + quad) ^ cswz) * 8];
            for (int mi = 0; mi < 2; mi++)
                for (int ni = 0; ni < 4; ni++)
                    acc[mi][ni] = MFMA16(af[mi], bfr[ni], acc[mi][ni]);
        }
        __syncthreads();
    }

    for (int mi = 0; mi < 2; mi++) {
        for (int ni = 0; ni < 4; ni++) {
            int mbase = bm + wm + mi * 16 + quad * 4;
            int n = bn + wn + ni * 16 + col;
            float bov = BO[n];
            for (int r = 0; r < 4; r++) {
                int m = mbase + r;
                OUT[(size_t)m * 1024 + n] = acc[mi][ni][r] + bov;
            }
        }
    }
}

// ---------------------------------------------------------------------------
extern "C" void kernel_launch(void* const* d_in, const int* in_sizes, int n_in,
                              void* d_out, int out_size, void* d_ws, size_t ws_size,
                              hipStream_t stream) {
    const float* x  = (const float*)d_in[0];
    const float* Wq = (const float*)d_in[1];
    const float* Wk = (const float*)d_in[2];
    const float* Wv = (const float*)d_in[3];
    const float* Wo = (const float*)d_in[4];
    const float* bo = (const float*)d_in[5];
    float* out = (float*)d_out;

    const size_t MEG = 1048576;
    bf16_t* base  = (bf16_t*)d_ws;
    bf16_t* Xb    = base;                 // 4M elems  [4096][1024]
    bf16_t* WTqkv = base + 4 * MEG;       // 3M (WqT, WkT, WvT)
    bf16_t* WoT   = base + 7 * MEG;       // 1M
    bf16_t* Qb    = base + 8 * MEG;       // 4M  [32][2048][64]
    bf16_t* Kb    = base + 12 * MEG;      // 4M
    bf16_t* Vb    = base + 16 * MEG;      // 4M  [32][64][2048]
    bf16_t* Cb    = base + 20 * MEG;      // 4M  [4096][1024]

    prep<<<dim3(32, 32, 5), dim3(32, 8), 0, stream>>>(x, Wq, Wk, Wv, Wo,
                                                      Xb, WTqkv, WoT);
    gemm_qkv<<<768, 256, 0, stream>>>(Xb, WTqkv, Qb, Kb, Vb);
    attn<<<1024, 256, 0, stream>>>(Qb, Kb, Vb, Cb);
    gemm_out<<<512, 256, 0, stream>>>(Cb, WoT, bo, out);
}